// Round 3
// baseline (224.417 us; speedup 1.0000x reference)
//
#include <hip/hip_runtime.h>
#include <hip/hip_fp16.h>

// Trilinear 3D-LUT apply: lut [1,3,33,33,33] f32, x [8,3,1024,1024] f32 in [0,1]
// out [8,3,1024,1024] f32.
//
// R1: LDS-gather-bound (SQ_LDS_BANK_CONFLICT ~29% of cycles at 8 reads/pixel).
// Fixes:
//  - LUT stored in LDS as __half2 packed along b: ls[i]=(lut[i],lut[i+1]) ->
//    one 4B read yields both b-corners (4 reads/pixel). fp16 err ~2e-3 << 0.077.
//  - x in [0,1) => i0<=31 always; clamp i0=min(i0,31) and use UNCONDITIONAL
//    +D/+D2/+D2+D offsets (edge exact via f=1 lerp) -> compiler merges into
//    ds_read2_b32 (offset1=33), ~2 LDS issue slots/pixel.
//  - XCD swizzle: 3 channel-blocks of one chunk -> same XCD L2, x fetched once.
//  - nontemporal output stores keep the 99MB write stream out of L2.
// R2: compile fix — nontemporal builtin needs a native vector type, not HIP's
//     float4 class. Use ext_vector_type(4) for the vector loads/stores.

#define D   33
#define D2  (33 * 33)
#define D3  (33 * 33 * 33)      // 35937 half2 = 143,748 B LDS
#define HW  (1024 * 1024)
#define BATCH 8
#define QHW (HW / 4)            // float4 groups per plane (2^18)
#define NG  (BATCH * QHW)       // float4 groups per channel
#define CHUNKS 256
#define GPC (NG / CHUNKS)       // groups per chunk = 8192
#define THREADS 1024

typedef float v4f __attribute__((ext_vector_type(4)));

__global__ __launch_bounds__(THREADS) void lut3d_kernel(
    const float* __restrict__ lut, const float* __restrict__ x,
    float* __restrict__ out)
{
    // XCD-aware swizzle (heuristic block->XCD = id%8): the 3 channel-blocks of
    // a chunk share an XCD and are near-co-resident -> x read once per XCD.
    const int id    = blockIdx.x;       // 0..767
    const int xcd   = id & 7;
    const int slot  = id >> 3;          // 0..95
    const int c     = slot % 3;         // output channel
    const int chunk = (slot / 3) * 8 + xcd;   // 0..255, bijective

    __shared__ __half2 ls[D3];
    {
        const float* lc = lut + c * D3;
        for (int i = threadIdx.x; i < D3; i += THREADS) {
            const int q  = i / D;           // magic-mul div by 33
            const int b  = i - q * D;       // i % 33
            const float v0 = lc[i];
            const float v1 = (b < D - 1) ? lc[i + 1] : v0;
            ls[i] = __floats2half2_rn(v0, v1);
        }
    }
    __syncthreads();

    const int tid  = threadIdx.x;
    const int base = chunk * GPC;

    #pragma unroll 1
    for (int it = 0; it < GPC / THREADS; ++it) {
        const int g = base + it * THREADS + tid;       // float4-group id
        const int b = g >> 18;                         // batch index
        const int p = (g & (QHW - 1)) * 4;             // pixel offset in plane

        const float* xb = x + (size_t)b * 3 * HW + p;
        const v4f xr = *(const v4f*)(xb);
        const v4f xg = *(const v4f*)(xb + HW);
        const v4f xB = *(const v4f*)(xb + 2 * HW);

        v4f oo;

        #pragma unroll
        for (int j = 0; j < 4; ++j) {
            const float vr = fminf(fmaxf(xr[j], 0.f), 1.f) * 32.f;
            const float vg = fminf(fmaxf(xg[j], 0.f), 1.f) * 32.f;
            const float vb = fminf(fmaxf(xB[j], 0.f), 1.f) * 32.f;

            // v >= 0 so (int) == floor; clamp to D-2 and let f=1 handle the
            // (unreachable for x<1) top edge exactly.
            const int r0 = min((int)vr, D - 2);
            const int g0 = min((int)vg, D - 2);
            const int b0 = min((int)vb, D - 2);
            const float fr = vr - (float)r0;
            const float fg = vg - (float)g0;
            const float fb = vb - (float)b0;

            const int idx = r0 * D2 + g0 * D + b0;

            // Each half2 = (c at b0, c at b0+1). Constant offsets -> ds_read2.
            const __half2 h00 = ls[idx];
            const __half2 h01 = ls[idx + D];
            const __half2 h10 = ls[idx + D2];
            const __half2 h11 = ls[idx + D2 + D];

            const float c00 = fmaf(fb, __high2float(h00) - __low2float(h00), __low2float(h00));
            const float c01 = fmaf(fb, __high2float(h01) - __low2float(h01), __low2float(h01));
            const float c10 = fmaf(fb, __high2float(h10) - __low2float(h10), __low2float(h10));
            const float c11 = fmaf(fb, __high2float(h11) - __low2float(h11), __low2float(h11));

            const float c0 = fmaf(fg, c01 - c00, c00);
            const float c1 = fmaf(fg, c11 - c10, c10);
            oo[j] = fmaf(fr, c1 - c0, c0);
        }

        float* ob = out + (size_t)b * 3 * HW + (size_t)c * HW + p;
        __builtin_nontemporal_store(oo, (v4f*)ob);
    }
}

extern "C" void kernel_launch(void* const* d_in, const int* in_sizes, int n_in,
                              void* d_out, int out_size, void* d_ws, size_t ws_size,
                              hipStream_t stream) {
    const float* lut = (const float*)d_in[0];   // [1,3,33,33,33]
    const float* x   = (const float*)d_in[1];   // [8,3,1024,1024]
    float* out = (float*)d_out;                 // [8,3,1024,1024]

    lut3d_kernel<<<dim3(3 * CHUNKS), THREADS, 0, stream>>>(lut, x, out);
}